// Round 2
// baseline (361.893 us; speedup 1.0000x reference)
//
#include <hip/hip_runtime.h>
#include <hip/hip_bf16.h>
#include <stdint.h>
#include <stddef.h>

// Problem constants
#define BATCH   4096
#define INDIM   512
#define OUTDIM  512
#define NH      32
#define KKDIM   64                 // 2*NH k-values per input dim
#define INV2PI  0.15915494309189535f

// Main-kernel tiling: 256 threads = 4 waves (2x2 grid of 64x64 wave tiles)
#define BM       128
#define BN       128
#define THREADS  256
#define KSPLIT   4
#define DIMS_PER_WG (INDIM / KSPLIT)   // 128 input dims per workgroup
#define NCOLB    (OUTDIM / BN)         // 4 column blocks
#define CHUNK_ELEMS (BN * KKDIM)       // 8192 bf16 = 16 KB per (colblock, dim) chunk

// LDS layout (bytes): A double-buffer + x double-buffer. B never touches LDS.
#define A_STRIDE 72                         // bf16 per row (64 + 8 pad; 9 16B-units/row -> conflict-free b128)
#define A_BYTES  (BM * A_STRIDE * 2)        // 18432
#define OFF_X    (2 * A_BYTES)              // 36864; 2 x-chunks of [8 dims][128 rows] f32
#define SMEM_BYTES (OFF_X + 2 * 8 * BM * 4) // 45056 -> 2 blocks/CU (LDS-wise 3)

typedef short  bhalf8  __attribute__((ext_vector_type(8)));  // 8 bf16 (4 VGPRs)
typedef float  vfloat4 __attribute__((ext_vector_type(4)));

__device__ __forceinline__ unsigned pack_bf16(float a, float b) {
    union { __hip_bfloat162 h2; unsigned u; } cv;
    cv.h2 = __float22bfloat162_rn(float2{a, b});   // cos in low half (kk even), sin in high
    return cv.u;
}

// ---------------------------------------------------------------------------
// Prepass: fourier_coeffs fp32 [512,32,2,512] -> bf16 [cb][dim][col 128][kk 64]
// via LDS transpose. Reads coalesced (contiguous 512B per 32 lanes), LDS col
// stride 76 halves (152B -> word-stride 38 == 6 mod 32: 2-way write aliasing =
// free), coalesced uint2 global stores.
// ---------------------------------------------------------------------------
__global__ __launch_bounds__(256) void fkan_prepass(const float* __restrict__ coeffs,
                                                    unsigned short* __restrict__ Bt) {
    __shared__ unsigned short tl[BN * 76];     // 19456 B
    const int t   = threadIdx.x;
    const int cb  = blockIdx.x & 3;
    const int dim = blockIdx.x >> 2;
    const float* __restrict__ src = coeffs + (size_t)dim * (KKDIM * OUTDIM) + cb * BN;
#pragma unroll
    for (int s = 0; s < 2; ++s) {
        const int idx = t + s * 256;           // 512 work items
        const int kq  = idx >> 5;              // kk quad 0..15
        const int c4  = (idx & 31) * 4;        // col base 0..124
        float4 f[4];
#pragma unroll
        for (int r = 0; r < 4; ++r)
            f[r] = *(const float4*)(src + (size_t)(kq * 4 + r) * OUTDIM + c4);
#pragma unroll
        for (int k = 0; k < 4; ++k) {          // per col: 4 consecutive kk -> one b64
            uint2 w;
            w.x = pack_bf16(((const float*)&f[0])[k], ((const float*)&f[1])[k]);
            w.y = pack_bf16(((const float*)&f[2])[k], ((const float*)&f[3])[k]);
            *(uint2*)(tl + (c4 + k) * 76 + kq * 4) = w;
        }
    }
    __syncthreads();
    uint2* __restrict__ dst = (uint2*)(Bt + ((size_t)cb * INDIM + dim) * CHUNK_ELEMS);
#pragma unroll
    for (int s = 0; s < 8; ++s) {
        const int unit = t + s * 256;          // 2048 8B units
        const int col  = unit >> 4;
        const int s4   = unit & 15;
        dst[unit] = *(const uint2*)(tl + col * 76 + s4 * 4);
    }
}

// out[b,o] = bias[o]
__global__ __launch_bounds__(256) void fkan_bias_init(const float* __restrict__ bias,
                                                      float* __restrict__ out) {
    const int idx = blockIdx.x * 256 + threadIdx.x;       // 524288 float4s
    ((float4*)out)[idx] = ((const float4*)bias)[idx & 127];
}

// ---------------------------------------------------------------------------
// Main kernel helpers
// ---------------------------------------------------------------------------
__device__ __forceinline__ void stage_x(const float* __restrict__ x, char* smem,
                                        int rowbase, int dimbase, int cn, int t) {
    const int r  = t >> 1;
    const int d0 = (t & 1) * 4;
    const float4 xv = *(const float4*)(x + (size_t)(rowbase + r) * INDIM + dimbase + cn * 8 + d0);
    float* xr = (float*)(smem + OFF_X + (cn & 1) * 4096);  // [8 dims][128 rows] f32
    xr[(d0 + 0) * BM + r] = xv.x * INV2PI;                 // store revolutions
    xr[(d0 + 1) * BM + r] = xv.y * INV2PI;
    xr[(d0 + 2) * BM + r] = xv.z * INV2PI;
    xr[(d0 + 3) * BM + r] = xv.w * INV2PI;
}

// cos/sin(k*x) for 16 harmonics (k = 16*tq+1 .. +16) via complex recurrence,
// packed bf16 pairs into A_lds[row][kk], padded stride 72 halves.
__device__ __forceinline__ void do_trig(char* smem, int dim_local, int parity, int trow, int tq) {
    const float rv = ((const float*)(smem + OFF_X + ((dim_local >> 3) & 1) * 4096))
                     [(dim_local & 7) * BM + trow];
    const float cd = __builtin_amdgcn_cosf(rv);   // e^{i x} (revolution domain)
    const float sd = __builtin_amdgcn_sinf(rv);
    const float a0 = (float)(tq * 16 + 1) * rv;
    float c = __builtin_amdgcn_cosf(a0);
    float s = __builtin_amdgcn_sinf(a0);
    unsigned pk[16];
    pk[0] = pack_bf16(c, s);
#pragma unroll
    for (int j = 1; j < 16; ++j) {
        const float nc = c * cd - s * sd;
        const float ns = s * cd + c * sd;
        c = nc; s = ns;
        pk[j] = pack_bf16(c, s);
    }
    uint4* adst = (uint4*)(smem + parity * A_BYTES + trow * (A_STRIDE * 2) + tq * 64);
#pragma unroll
    for (int q = 0; q < 4; ++q) {
        uint4 w; w.x = pk[q * 4]; w.y = pk[q * 4 + 1]; w.z = pk[q * 4 + 2]; w.w = pk[q * 4 + 3];
        adst[q] = w;
    }
}

// One K-iteration with compile-time parity P. B fragments for iter it+1 are
// prefetched from global into `nxt` (registers) while MFMA consumes `cur`;
// trig for it+1 (VALU) overlaps MFMA; single barrier guards the A/x LDS bufs.
template <int P>
__device__ __forceinline__ void fkan_step(int it, const float* __restrict__ x,
                                          const unsigned short* __restrict__ chunk0,
                                          char* smem, int rowbase, int dimbase,
                                          const int (&boff)[8],
                                          bhalf8 (&cur)[8], bhalf8 (&nxt)[8],
                                          vfloat4 (&acc)[4][4],
                                          int t, int wr, int wc, int fr, int fq,
                                          int trow, int tq) {
    const int inxt = it + 1;
    if (inxt < DIMS_PER_WG) {
        const unsigned short* ch = chunk0 + (size_t)inxt * CHUNK_ELEMS;
#pragma unroll
        for (int j = 0; j < 8; ++j)
            nxt[j] = *(const bhalf8*)(ch + boff[j]);       // global_load_dwordx4
        if ((it & 7) == 0) {
            const int cn = (it >> 3) + 1;
            if (cn < 16) stage_x(x, smem, rowbase, dimbase, cn, t);
        }
        do_trig(smem, inxt, P ^ 1, trow, tq);
    }
    const char* Ab = smem + P * A_BYTES;
#pragma unroll
    for (int ks = 0; ks < 2; ++ks) {
        bhalf8 av[4];
#pragma unroll
        for (int rt = 0; rt < 4; ++rt)
            av[rt] = *(const bhalf8*)(Ab + (wr * 64 + rt * 16 + fr) * (A_STRIDE * 2)
                                         + ks * 64 + fq * 16);
#pragma unroll
        for (int rt = 0; rt < 4; ++rt)
#pragma unroll
            for (int ct = 0; ct < 4; ++ct)
                acc[rt][ct] = __builtin_amdgcn_mfma_f32_16x16x32_bf16(
                    av[rt], cur[ks * 4 + ct], acc[rt][ct], 0, 0, 0);
    }
    __syncthreads();
}

// ---------------------------------------------------------------------------
// Main kernel: grid 512 = 32 rowblocks x 4 colblocks x 4 ksplits, 256 thr.
// blockIdx&15 -> (cb,kq) group; round-robin XCD mapping gives each XCD two
// groups whose combined bf16 B working set is 4 MB = its L2.
// ---------------------------------------------------------------------------
__global__ __launch_bounds__(THREADS, 2) void fkan_main(const float* __restrict__ x,
                                                        const unsigned short* __restrict__ Bt,
                                                        float* __restrict__ out) {
    __shared__ char smem[SMEM_BYTES];
    const int t       = threadIdx.x;
    const int grp     = blockIdx.x & 15;
    const int member  = blockIdx.x >> 4;
    const int cb      = grp & 3;
    const int kq      = grp >> 2;
    const int rowbase = member * BM;
    const int colbase = cb * BN;
    const int dimbase = kq * DIMS_PER_WG;

    const int lane = t & 63;
    const int w    = t >> 6;       // 4 waves: 2 rows x 2 cols, 64x64 tiles
    const int wr   = w >> 1;
    const int wc   = w & 1;
    const int fr   = lane & 15;
    const int fq   = lane >> 4;

    const int trow = t & 127;      // trig: 2 threads per row, 16 harmonics each
    const int tq   = t >> 7;

    const unsigned short* chunk0 = Bt + ((size_t)cb * INDIM + dimbase) * CHUNK_ELEMS;
    int boff[8];                   // per-lane half-offsets for the 8 B loads
#pragma unroll
    for (int ks = 0; ks < 2; ++ks)
#pragma unroll
        for (int ct = 0; ct < 4; ++ct)
            boff[ks * 4 + ct] = (wc * 64 + ct * 16 + fr) * KKDIM + (ks * 4 + fq) * 8;

    vfloat4 acc[4][4];
#pragma unroll
    for (int a = 0; a < 4; ++a)
#pragma unroll
        for (int b = 0; b < 4; ++b) acc[a][b] = (vfloat4)0.0f;

    // Prologue: x chunk 0 -> trig dim 0 into A[0]; B frags for it=0.
    stage_x(x, smem, rowbase, dimbase, 0, t);
    __syncthreads();
    do_trig(smem, 0, 0, trow, tq);
    bhalf8 bv0[8], bv1[8];
#pragma unroll
    for (int j = 0; j < 8; ++j)
        bv0[j] = *(const bhalf8*)(chunk0 + boff[j]);
    __syncthreads();

    for (int it = 0; it < DIMS_PER_WG; it += 2) {
        fkan_step<0>(it,     x, chunk0, smem, rowbase, dimbase, boff, bv0, bv1, acc,
                     t, wr, wc, fr, fq, trow, tq);
        fkan_step<1>(it + 1, x, chunk0, smem, rowbase, dimbase, boff, bv1, bv0, acc,
                     t, wr, wc, fr, fq, trow, tq);
    }

    // Epilogue: C/D layout col=lane&15, row=quad*4+reg (m89). KSPLIT via atomics.
#pragma unroll
    for (int rt = 0; rt < 4; ++rt) {
#pragma unroll
        for (int ct = 0; ct < 4; ++ct) {
            const int col  = colbase + wc * 64 + ct * 16 + fr;
            const int row0 = rowbase + wr * 64 + rt * 16 + fq * 4;
#pragma unroll
            for (int r = 0; r < 4; ++r)
                atomicAdd(out + (size_t)(row0 + r) * OUTDIM + col, acc[rt][ct][r]);
        }
    }
}

// ---------------------------------------------------------------------------
// Fallback (only if ws too small for the 32MB bf16 B): slow but correct fp32.
// ---------------------------------------------------------------------------
__global__ __launch_bounds__(256) void fkan_naive(const float* __restrict__ x,
                                                  const float* __restrict__ coeffs,
                                                  const float* __restrict__ bias,
                                                  float* __restrict__ out) {
    const int b = blockIdx.x >> 1;
    const int o = ((blockIdx.x & 1) << 8) + threadIdx.x;
    float acc = bias[o];
    const float* xrow = x + (size_t)b * INDIM;
    for (int i = 0; i < INDIM; ++i) {
        const float rv = xrow[i] * INV2PI;
        const float cd = __builtin_amdgcn_cosf(rv);
        const float sd = __builtin_amdgcn_sinf(rv);
        float c = cd, s = sd;
        const float* cp = coeffs + (size_t)i * (KKDIM * OUTDIM) + o;
#pragma unroll 4
        for (int g = 0; g < NH; ++g) {
            acc += c * cp[g * 2 * OUTDIM] + s * cp[(g * 2 + 1) * OUTDIM];
            const float nc = c * cd - s * sd;
            const float ns = s * cd + c * sd;
            c = nc; s = ns;
        }
    }
    out[(size_t)b * OUTDIM + o] = acc;
}

extern "C" void kernel_launch(void* const* d_in, const int* in_sizes, int n_in,
                              void* d_out, int out_size, void* d_ws, size_t ws_size,
                              hipStream_t stream) {
    (void)in_sizes; (void)n_in; (void)out_size;
    const float* x      = (const float*)d_in[0];
    const float* coeffs = (const float*)d_in[1];
    const float* bias   = (const float*)d_in[2];
    float* out          = (float*)d_out;

    const size_t bt_bytes = (size_t)NCOLB * INDIM * CHUNK_ELEMS * sizeof(unsigned short); // 32 MiB
    if (ws_size >= bt_bytes) {
        unsigned short* Bt = (unsigned short*)d_ws;
        fkan_prepass<<<NCOLB * INDIM, 256, 0, stream>>>(coeffs, Bt);       // 2048 blocks
        fkan_bias_init<<<(BATCH * OUTDIM) / (4 * 256), 256, 0, stream>>>(bias, out);
        fkan_main<<<(BATCH / BM) * NCOLB * KSPLIT, THREADS, 0, stream>>>(x, Bt, out); // 512
    } else {
        fkan_naive<<<BATCH * 2, 256, 0, stream>>>(x, coeffs, bias, out);
    }
}

// Round 3
// 354.783 us; speedup vs baseline: 1.0200x; 1.0200x over previous
//
#include <hip/hip_runtime.h>
#include <hip/hip_bf16.h>
#include <stdint.h>
#include <stddef.h>

// Problem constants
#define BATCH   4096
#define INDIM   512
#define OUTDIM  512
#define NH      32
#define KKDIM   64                 // 2*NH k-values per input dim
#define INV2PI  0.15915494309189535f

// Main-kernel tiling: 512 threads = 8 waves (2x4 grid of 64x64 wave tiles),
// each wave tile = 2x2 of 32x32x16 MFMA, BK per dim = 64 (4 k-steps of 16).
#define BM       128
#define BN       256
#define THREADS  512
#define KSPLIT   4
#define DIMS_PER_WG (INDIM / KSPLIT)   // 128 input dims per workgroup
#define PERIODS  (DIMS_PER_WG / 2)     // 64 barrier periods (2 dims each)
#define CHUNK_ELEMS (BN * KKDIM)       // 16384 bf16 = 32 KB per (colblock, dim) chunk
#define CHUNK_BYTES (CHUNK_ELEMS * 2)

// LDS: 2 x 64KB B buffers (2 dims each, exact global_load_lds image) + 2 x 4KB x-chunks.
#define OFF_XS     131072
#define SMEM_BYTES (OFF_XS + 2 * 8 * BM * 4)   // 139264

typedef short  bhalf8   __attribute__((ext_vector_type(8)));   // 8 bf16 (4 VGPRs)
typedef float  vfloat16 __attribute__((ext_vector_type(16)));  // 32x32 accumulator

__device__ __forceinline__ unsigned pack_bf16(float a, float b) {
    union { __hip_bfloat162 h2; unsigned u; } cv;
    cv.h2 = __float22bfloat162_rn(float2{a, b});   // cos in low half (kk even), sin in high
    return cv.u;
}

__device__ __forceinline__ void async_copy16(const void* gsrc, void* ldst) {
    __builtin_amdgcn_global_load_lds(
        (const __attribute__((address_space(1))) void*)(uintptr_t)gsrc,
        (__attribute__((address_space(3))) void*)(uint32_t)(uintptr_t)ldst,
        16, 0, 0);
}

// ---------------------------------------------------------------------------
// Prepass: fourier_coeffs fp32 [512,32,2,512] -> bf16 chunks [cb][dim][col 256][unit 8]
// where 16B unit u of col holds kk = 8u..8u+7 (4 (cos,sin) dword pairs), stored at
// physical slot p = u ^ (col&7) (bank swizzle baked into the global image so the
// main kernel's global_load_lds copy needs no per-lane address math).
// Fully coalesced reads (1KB/row/wave) and stores (4KB/wave).
// ---------------------------------------------------------------------------
__global__ __launch_bounds__(256) void fkan_prepass(const float* __restrict__ coeffs,
                                                    unsigned short* __restrict__ Bt) {
    __shared__ char tl[32768];
    const int t   = threadIdx.x;
    const int cb  = blockIdx.x & 1;
    const int dim = blockIdx.x >> 1;
    const float* __restrict__ src = coeffs + (size_t)dim * (KKDIM * OUTDIM) + cb * BN;
#pragma unroll
    for (int s = 0; s < 2; ++s) {
        const int idx = t + s * 256;           // 512 items = 8 units x 64 col-groups
        const int u   = idx >> 6;
        const int c4  = (idx & 63) * 4;
        float4 f[8];
#pragma unroll
        for (int j = 0; j < 8; ++j)
            f[j] = *(const float4*)(src + (size_t)(u * 8 + j) * OUTDIM + c4);
        const float* fp = (const float*)f;
#pragma unroll
        for (int i = 0; i < 4; ++i) {
            const int col = c4 + i;
            uint4 o;
            o.x = pack_bf16(fp[0 * 4 + i], fp[1 * 4 + i]);
            o.y = pack_bf16(fp[2 * 4 + i], fp[3 * 4 + i]);
            o.z = pack_bf16(fp[4 * 4 + i], fp[5 * 4 + i]);
            o.w = pack_bf16(fp[6 * 4 + i], fp[7 * 4 + i]);
            *(uint4*)(tl + col * 128 + (u ^ (col & 7)) * 16) = o;
        }
    }
    __syncthreads();
    uint4* __restrict__ dst = (uint4*)(Bt + ((size_t)cb * INDIM + dim) * CHUNK_ELEMS);
    const uint4* tls = (const uint4*)tl;
#pragma unroll
    for (int s = 0; s < 8; ++s) {
        const int unit = t + s * 256;          // linear: LDS read conflict-free, store coalesced
        dst[unit] = tls[unit];
    }
}

// out[b,o] = bias[o]
__global__ __launch_bounds__(256) void fkan_bias_init(const float* __restrict__ bias,
                                                      float* __restrict__ out) {
    const int idx = blockIdx.x * 256 + threadIdx.x;       // 524288 float4s
    ((float4*)out)[idx] = ((const float4*)bias)[idx & 127];
}

// ---------------------------------------------------------------------------
// Main kernel helpers
// ---------------------------------------------------------------------------
__device__ __forceinline__ void stage_B2(const unsigned short* __restrict__ chunk0,
                                         char* smem, int d0, int bufq, int t) {
    const char* src = (const char*)chunk0 + (size_t)d0 * CHUNK_BYTES;   // 64 KB, 2 dims
    char* dst = smem + bufq * 65536;
#pragma unroll
    for (int r = 0; r < 8; ++r) {
        const int off = (r * 512 + t) * 16;
        async_copy16(src + off, dst + off);    // dest = wave-uniform base + lane*16
    }
}

// Stage x chunk c (8 dims x 128 rows, stored as revolutions) into xs buf c&1.
__device__ __forceinline__ void stage_x(const float* __restrict__ x, char* smem,
                                        int rowbase, int dimbase, int c, int t) {
    const int r  = t & 127;
    const int dp = t >> 7;                     // 4 dim-pairs
    const float2 xv = *(const float2*)(x + (size_t)(rowbase + r) * INDIM + dimbase + c * 8 + dp * 2);
    float* xr = (float*)(smem + OFF_XS + (c & 1) * 4096);
    xr[(dp * 2 + 0) * BM + r] = xv.x * INV2PI;
    xr[(dp * 2 + 1) * BM + r] = xv.y * INV2PI;
}

// cos/sin((h)*2pi*tr) for h = 4*half+1 + ks*8 + j (ks=0..3, j=0..3), packed as
// dword pairs matching the 32x32x16 A-operand fragment (k = 8*half + j-pairs).
__device__ __forceinline__ void gen_row(float tr, int half, unsigned (&pk)[16]) {
    const float c1 = __builtin_amdgcn_cosf(tr);
    const float s1 = __builtin_amdgcn_sinf(tr);
    const float c2 = c1 * c1 - s1 * s1, s2 = 2.f * c1 * s1;
    const float c4 = c2 * c2 - s2 * s2, s4 = 2.f * c2 * s2;
    const float c8 = c4 * c4 - s4 * s4, s8 = 2.f * c4 * s4;
    const float c5 = c1 * c4 - s1 * s4, s5 = s1 * c4 + c1 * s4;
    float fc = half ? c5 : c1;                 // base harmonic h0 = 4*half + 1
    float fs = half ? s5 : s1;
#pragma unroll
    for (int ks = 0; ks < 4; ++ks) {
        float gc = fc, gs = fs;
        pk[ks * 4 + 0] = pack_bf16(gc, gs);
#pragma unroll
        for (int j = 1; j < 4; ++j) {
            const float nc = gc * c1 - gs * s1;
            const float ns = gs * c1 + gc * s1;
            gc = nc; gs = ns;
            pk[ks * 4 + j] = pack_bf16(gc, gs);
        }
        if (ks < 3) {                          // hop +8 harmonics
            const float nc = fc * c8 - fs * s8;
            const float ns = fs * c8 + fc * s8;
            fc = nc; fs = ns;
        }
    }
}

// Generate both A-fragment rows (rt=0,1) for dim dn into dst (register-only).
__device__ __forceinline__ void gen_dim(const char* smem, int dn, int lrow0, int half,
                                        bhalf8 (&dst)[2][4]) {
    const float* xs = (const float*)(smem + OFF_XS + ((dn >> 3) & 1) * 4096) + (dn & 7) * BM;
#pragma unroll
    for (int rt = 0; rt < 2; ++rt) {
        const float tr = xs[lrow0 + rt * 32];
        unsigned pk[16];
        gen_row(tr, half, pk);
#pragma unroll
        for (int ks = 0; ks < 4; ++ks) {
            union { unsigned u[4]; bhalf8 v; } cv;
            cv.u[0] = pk[ks * 4 + 0]; cv.u[1] = pk[ks * 4 + 1];
            cv.u[2] = pk[ks * 4 + 2]; cv.u[3] = pk[ks * 4 + 3];
            dst[rt][ks] = cv.v;
        }
    }
}

// ---------------------------------------------------------------------------
// Main kernel: grid 256 = 32 rowblocks x (2 colblocks x 4 ksplits), 512 thr.
// blockIdx&7 -> (cb,kq): one group per XCD; its 128-dim B slice = 4MB = L2.
// A-fragments generated in registers (no LDS round-trip); B double-buffered
// via global_load_lds, 2 dims per barrier.
// ---------------------------------------------------------------------------
__global__ __launch_bounds__(THREADS, 2) void fkan_main(const float* __restrict__ x,
                                                        const unsigned short* __restrict__ Bt,
                                                        float* __restrict__ out) {
    __shared__ char smem[SMEM_BYTES];
    const int t       = threadIdx.x;
    const int grp     = blockIdx.x & 7;
    const int member  = blockIdx.x >> 3;
    const int cb      = grp & 1;
    const int kq      = grp >> 1;
    const int rowbase = member * BM;
    const int colbase = cb * BN;
    const int dimbase = kq * DIMS_PER_WG;

    const int lane = t & 63;
    const int w    = t >> 6;       // 8 waves: 2 rows x 4 cols of 64x64 tiles
    const int wr   = w >> 2;
    const int wc   = w & 3;
    const int l31  = lane & 31;
    const int half = lane >> 5;
    const int lrow0 = wr * 64 + l31;           // block-local A row (rt adds +32)

    const unsigned short* chunk0 = Bt + ((size_t)cb * INDIM + dimbase) * CHUNK_ELEMS;

    // Per-lane B-fragment LDS offsets (col = wc*64 + ct*32 + l31, swizzled unit).
    int coladdr[2], ksoff[4];
#pragma unroll
    for (int ct = 0; ct < 2; ++ct) coladdr[ct] = (wc * 64 + ct * 32 + l31) * 128;
#pragma unroll
    for (int ks = 0; ks < 4; ++ks) ksoff[ks] = ((ks * 2 + half) ^ (lane & 7)) * 16;

    vfloat16 acc[2][2];
#pragma unroll
    for (int a = 0; a < 2; ++a)
#pragma unroll
        for (int b = 0; b < 2; ++b) acc[a][b] = (vfloat16)0.0f;

    bhalf8 areg[2][2][4];          // [dim parity][rt][ks]

    // Prologue: x chunk 0, B dims 0,1 -> buf0; then A(0) in registers.
    stage_x(x, smem, rowbase, dimbase, 0, t);
    stage_B2(chunk0, smem, 0, 0, t);
    __syncthreads();
    gen_dim(smem, 0, lrow0, half, areg[0]);

    for (int p = 0; p < PERIODS; ++p) {
        const int q = p & 1;
        if ((p & 3) == 2) {                    // stage x chunk (p+2)/4 (dims 8c..8c+7)
            const int c = (p + 2) >> 2;
            if (c < 16) stage_x(x, smem, rowbase, dimbase, c, t);
        }
        if (p < PERIODS - 1)                   // async B for next period
            stage_B2(chunk0, smem, 2 * p + 2, 1 - q, t);

#pragma unroll
        for (int h = 0; h < 2; ++h) {          // two dims per period
            const int d = 2 * p + h;
            const char* bb = smem + q * 65536 + h * 32768;
            bhalf8 bv[2][4];
#pragma unroll
            for (int ks = 0; ks < 4; ++ks)
#pragma unroll
                for (int ct = 0; ct < 2; ++ct)
                    bv[ct][ks] = *(const bhalf8*)(bb + coladdr[ct] + ksoff[ks]);
            if (d + 1 < DIMS_PER_WG)           // register-only A for next dim (VALU, overlaps MFMA)
                gen_dim(smem, d + 1, lrow0, half, areg[1 - h]);
#pragma unroll
            for (int ks = 0; ks < 4; ++ks)
#pragma unroll
                for (int rt = 0; rt < 2; ++rt)
#pragma unroll
                    for (int ct = 0; ct < 2; ++ct)
                        acc[rt][ct] = __builtin_amdgcn_mfma_f32_32x32x16_bf16(
                            areg[h][rt][ks], bv[ct][ks], acc[rt][ct], 0, 0, 0);
        }
        __syncthreads();
    }

    // Epilogue: 32x32 C/D layout col=lane&31, row=(reg&3)+8*(reg>>2)+4*(lane>>5)
    // [measured m74/m101]. KSPLIT partials via device-scope atomics.
#pragma unroll
    for (int rt = 0; rt < 2; ++rt) {
#pragma unroll
        for (int ct = 0; ct < 2; ++ct) {
            const int col   = colbase + wc * 64 + ct * 32 + l31;
            const int rbase = rowbase + wr * 64 + rt * 32 + 4 * half;
#pragma unroll
            for (int reg = 0; reg < 16; ++reg) {
                const int row = rbase + (reg & 3) + 8 * (reg >> 2);
                atomicAdd(out + (size_t)row * OUTDIM + col, acc[rt][ct][reg]);
            }
        }
    }
}

// ---------------------------------------------------------------------------
// Fallback (only if ws too small for the 32MB bf16 B): slow but correct fp32.
// ---------------------------------------------------------------------------
__global__ __launch_bounds__(256) void fkan_naive(const float* __restrict__ x,
                                                  const float* __restrict__ coeffs,
                                                  const float* __restrict__ bias,
                                                  float* __restrict__ out) {
    const int b = blockIdx.x >> 1;
    const int o = ((blockIdx.x & 1) << 8) + threadIdx.x;
    float acc = bias[o];
    const float* xrow = x + (size_t)b * INDIM;
    for (int i = 0; i < INDIM; ++i) {
        const float rv = xrow[i] * INV2PI;
        const float cd = __builtin_amdgcn_cosf(rv);
        const float sd = __builtin_amdgcn_sinf(rv);
        float c = cd, s = sd;
        const float* cp = coeffs + (size_t)i * (KKDIM * OUTDIM) + o;
#pragma unroll 4
        for (int g = 0; g < NH; ++g) {
            acc += c * cp[g * 2 * OUTDIM] + s * cp[(g * 2 + 1) * OUTDIM];
            const float nc = c * cd - s * sd;
            const float ns = s * cd + c * sd;
            c = nc; s = ns;
        }
    }
    out[(size_t)b * OUTDIM + o] = acc;
}

extern "C" void kernel_launch(void* const* d_in, const int* in_sizes, int n_in,
                              void* d_out, int out_size, void* d_ws, size_t ws_size,
                              hipStream_t stream) {
    (void)in_sizes; (void)n_in; (void)out_size;
    const float* x      = (const float*)d_in[0];
    const float* coeffs = (const float*)d_in[1];
    const float* bias   = (const float*)d_in[2];
    float* out          = (float*)d_out;

    const size_t bt_bytes = (size_t)2 * INDIM * CHUNK_ELEMS * sizeof(unsigned short); // 32 MiB
    if (ws_size >= bt_bytes) {
        unsigned short* Bt = (unsigned short*)d_ws;
        fkan_prepass<<<2 * INDIM, 256, 0, stream>>>(coeffs, Bt);           // 1024 blocks
        fkan_bias_init<<<(BATCH * OUTDIM) / (4 * 256), 256, 0, stream>>>(bias, out);
        fkan_main<<<(BATCH / BM) * 2 * KSPLIT, THREADS, 0, stream>>>(x, Bt, out);  // 256 blocks
    } else {
        fkan_naive<<<BATCH * 2, 256, 0, stream>>>(x, coeffs, bias, out);
    }
}

// Round 5
// 339.341 us; speedup vs baseline: 1.0665x; 1.0455x over previous
//
#include <hip/hip_runtime.h>
#include <hip/hip_bf16.h>
#include <stdint.h>
#include <stddef.h>

// Problem constants
#define BATCH   4096
#define INDIM   512
#define OUTDIM  512
#define NH      32
#define KKDIM   64                 // 2*NH k-values per input dim
#define INV2PI  0.15915494309189535f

// Main-kernel tiling: 512 threads = 8 waves (2x4 grid of 64x64 wave tiles),
// each wave tile = 2x2 of 32x32x16 MFMA, BK per dim = 64 (4 k-steps of 16).
#define BM       128
#define BN       256
#define THREADS  512
#define KSPLIT   4
#define DIMS_PER_WG (INDIM / KSPLIT)   // 128 input dims per workgroup
#define PERIODS  (DIMS_PER_WG / 2)     // 64 barrier periods (2 dims each)
#define CHUNK_ELEMS (BN * KKDIM)       // 16384 bf16 = 32 KB per (colblock, dim) chunk
#define CHUNK_BYTES (CHUNK_ELEMS * 2)

// LDS: 2 x 64KB B buffers (2 dims each, exact global_load_lds image) + 2 x 4KB x-chunks.
#define OFF_XS     131072
#define SMEM_BYTES (OFF_XS + 2 * 8 * BM * 4)   // 139264 -> 1 block/CU

typedef short  bhalf8   __attribute__((ext_vector_type(8)));   // 8 bf16 (4 VGPRs)
typedef float  vfloat16 __attribute__((ext_vector_type(16)));  // 32x32 accumulator

// Hardware packed f32->bf16 convert (one VOP3, gfx950 instruction). The
// hip_bf16 header's software RNE (~14 VALU/pair) was the R3 VALU bottleneck.
__device__ __forceinline__ unsigned pack_bf16(float a, float b) {
    unsigned r;
    asm("v_cvt_pk_bf16_f32 %0, %1, %2" : "=v"(r) : "v"(a), "v"(b));
    return r;   // lo = bf16(a) = cos (kk even), hi = bf16(b) = sin
}

__device__ __forceinline__ void async_copy16(const void* gsrc, void* ldst) {
    __builtin_amdgcn_global_load_lds(
        (const __attribute__((address_space(1))) void*)(uintptr_t)gsrc,
        (__attribute__((address_space(3))) void*)(uint32_t)(uintptr_t)ldst,
        16, 0, 0);
}

// ---------------------------------------------------------------------------
// Prepass: fourier_coeffs fp32 [512,32,2,512] -> bf16 chunks [cb][dim][col 256][unit 8]
// where 16B unit u of col holds kk = 8u..8u+7 (4 (cos,sin) dword pairs) at
// physical slot u ^ (col&7) (bank swizzle baked into the global image).
// Fused: also initializes out[b,o] = bias[o]. out = 524288 float4s total ->
// 512 per block over 1024 blocks (R4's 2048/block overran out by 4x: crash).
// ---------------------------------------------------------------------------
__global__ __launch_bounds__(256) void fkan_prepass(const float* __restrict__ coeffs,
                                                    const float* __restrict__ bias,
                                                    float* __restrict__ out,
                                                    unsigned short* __restrict__ Bt) {
    __shared__ char tl[32768];
    const int t = threadIdx.x;
    // Fused out-init: 512 float4s per block.
    {
        const int base = blockIdx.x * 512 + t;
#pragma unroll
        for (int s = 0; s < 2; ++s) {
            const int idx = base + s * 256;
            ((float4*)out)[idx] = ((const float4*)bias)[idx & 127];
        }
    }
    const int cb  = blockIdx.x & 1;
    const int dim = blockIdx.x >> 1;
    const float* __restrict__ src = coeffs + (size_t)dim * (KKDIM * OUTDIM) + cb * BN;
#pragma unroll
    for (int s = 0; s < 2; ++s) {
        const int idx = t + s * 256;           // 512 items = 8 units x 64 col-groups
        const int u   = idx >> 6;
        const int c4  = (idx & 63) * 4;
        float4 f[8];
#pragma unroll
        for (int j = 0; j < 8; ++j)
            f[j] = *(const float4*)(src + (size_t)(u * 8 + j) * OUTDIM + c4);
        const float* fp = (const float*)f;
#pragma unroll
        for (int i = 0; i < 4; ++i) {
            const int col = c4 + i;
            uint4 o;
            o.x = pack_bf16(fp[0 * 4 + i], fp[1 * 4 + i]);
            o.y = pack_bf16(fp[2 * 4 + i], fp[3 * 4 + i]);
            o.z = pack_bf16(fp[4 * 4 + i], fp[5 * 4 + i]);
            o.w = pack_bf16(fp[6 * 4 + i], fp[7 * 4 + i]);
            *(uint4*)(tl + col * 128 + (u ^ (col & 7)) * 16) = o;
        }
    }
    __syncthreads();
    uint4* __restrict__ dst = (uint4*)(Bt + ((size_t)cb * INDIM + dim) * CHUNK_ELEMS);
    const uint4* tls = (const uint4*)tl;
#pragma unroll
    for (int s = 0; s < 8; ++s) {
        const int unit = t + s * 256;
        dst[unit] = tls[unit];
    }
}

// ---------------------------------------------------------------------------
// Main kernel helpers
// ---------------------------------------------------------------------------
__device__ __forceinline__ void stage_B2(const unsigned short* __restrict__ chunk0,
                                         char* smem, int d0, int bufq, int t) {
    const char* src = (const char*)chunk0 + (size_t)d0 * CHUNK_BYTES;   // 64 KB, 2 dims
    char* dst = smem + bufq * 65536;
#pragma unroll
    for (int r = 0; r < 8; ++r) {
        const int off = (r * 512 + t) * 16;
        async_copy16(src + off, dst + off);    // dest = wave-uniform base + lane*16
    }
}

// Stage x chunk c (8 dims x 128 rows, stored as revolutions) into xs buf c&1.
__device__ __forceinline__ void stage_x(const float* __restrict__ x, char* smem,
                                        int rowbase, int dimbase, int c, int t) {
    const int r  = t & 127;
    const int dp = t >> 7;                     // 4 dim-pairs
    const float2 xv = *(const float2*)(x + (size_t)(rowbase + r) * INDIM + dimbase + c * 8 + dp * 2);
    float* xr = (float*)(smem + OFF_XS + (c & 1) * 4096);
    xr[(dp * 2 + 0) * BM + r] = xv.x * INV2PI;
    xr[(dp * 2 + 1) * BM + r] = xv.y * INV2PI;
}

// cos/sin(h * 2pi * tr) for h = (4*half+1) + ks*8 + p (ks=0..3, p=0..3), built
// directly into the 4 A-operand fragments (no intermediate array).
__device__ __forceinline__ void gen_row_frags(float tr, int half, bhalf8 (&out)[4]) {
    const float c1 = __builtin_amdgcn_cosf(tr);
    const float s1 = __builtin_amdgcn_sinf(tr);
    const float c2 = c1 * c1 - s1 * s1, s2 = 2.f * c1 * s1;
    const float c4 = c2 * c2 - s2 * s2, s4 = 2.f * c2 * s2;
    const float c8 = c4 * c4 - s4 * s4, s8 = 2.f * c4 * s4;
    const float c5 = c1 * c4 - s1 * s4, s5 = s1 * c4 + c1 * s4;
    float fc = half ? c5 : c1;                 // base harmonic h0 = 4*half + 1
    float fs = half ? s5 : s1;
#pragma unroll
    for (int ks = 0; ks < 4; ++ks) {
        union { unsigned u[4]; bhalf8 v; } f;
        float gc = fc, gs = fs;
        f.u[0] = pack_bf16(gc, gs);
#pragma unroll
        for (int j = 1; j < 4; ++j) {
            const float nc = gc * c1 - gs * s1;
            const float ns = gs * c1 + gc * s1;
            gc = nc; gs = ns;
            f.u[j] = pack_bf16(gc, gs);
        }
        out[ks] = f.v;
        if (ks < 3) {                          // hop +8 harmonics
            const float nc = fc * c8 - fs * s8;
            const float ns = fs * c8 + fc * s8;
            fc = nc; fs = ns;
        }
    }
}

// Generate both A-fragment rows (rt=0,1) for dim dn (register-only).
__device__ __forceinline__ void gen_dim(const char* smem, int dn, int lrow0, int half,
                                        bhalf8 (&dst)[2][4]) {
    const float* xs = (const float*)(smem + OFF_XS + ((dn >> 3) & 1) * 4096) + (dn & 7) * BM;
#pragma unroll
    for (int rt = 0; rt < 2; ++rt)
        gen_row_frags(xs[lrow0 + rt * 32], half, dst[rt]);
}

// ---------------------------------------------------------------------------
// Main kernel: grid 256 = 32 rowblocks x (2 colblocks x 4 ksplits), 512 thr.
// blockIdx&7 -> (cb,kq): one group per XCD; its 128-dim B slice = 4MB = L2.
// A in registers, B double-buffered via global_load_lds, 2 dims per barrier;
// next-dim A-gen (VALU) slotted between the two MFMA blocks.
// ---------------------------------------------------------------------------
__global__ __launch_bounds__(THREADS, 2) void fkan_main(const float* __restrict__ x,
                                                        const unsigned short* __restrict__ Bt,
                                                        float* __restrict__ out) {
    __shared__ char smem[SMEM_BYTES];
    const int t       = threadIdx.x;
    const int grp     = blockIdx.x & 7;
    const int member  = blockIdx.x >> 3;
    const int cb      = grp & 1;
    const int kq      = grp >> 1;
    const int rowbase = member * BM;
    const int colbase = cb * BN;
    const int dimbase = kq * DIMS_PER_WG;

    const int lane = t & 63;
    const int w    = t >> 6;       // 8 waves: 2 rows x 4 cols of 64x64 tiles
    const int wr   = w >> 2;
    const int wc   = w & 3;
    const int l31  = lane & 31;
    const int half = lane >> 5;
    const int lrow0 = wr * 64 + l31;

    const unsigned short* chunk0 = Bt + ((size_t)cb * INDIM + dimbase) * CHUNK_ELEMS;

    // Per-lane B-fragment LDS offsets (col = wc*64 + ct*32 + l31, swizzled unit).
    int coladdr[2], ksoff[4];
#pragma unroll
    for (int ct = 0; ct < 2; ++ct) coladdr[ct] = (wc * 64 + ct * 32 + l31) * 128;
#pragma unroll
    for (int ks = 0; ks < 4; ++ks) ksoff[ks] = ((ks * 2 + half) ^ (lane & 7)) * 16;

    vfloat16 acc[2][2];
#pragma unroll
    for (int a = 0; a < 2; ++a)
#pragma unroll
        for (int b = 0; b < 2; ++b) acc[a][b] = (vfloat16)0.0f;

    bhalf8 areg[2][2][4];          // [dim parity][rt][ks]

    // Prologue: x chunk 0, B dims 0,1 -> buf0; A(dim 0) in registers.
    stage_x(x, smem, rowbase, dimbase, 0, t);
    stage_B2(chunk0, smem, 0, 0, t);
    __syncthreads();
    gen_dim(smem, 0, lrow0, half, areg[0]);

    for (int p = 0; p < PERIODS; ++p) {
        const int q = p & 1;
        if ((p & 3) == 2) {                    // stage x chunk (p+2)/4
            const int c = (p + 2) >> 2;
            if (c < 16) stage_x(x, smem, rowbase, dimbase, c, t);
        }
        if (p < PERIODS - 1)                   // async B for next period
            stage_B2(chunk0, smem, 2 * p + 2, 1 - q, t);

        const char* bb = smem + q * 65536;
        bhalf8 bvA[2][4];
#pragma unroll
        for (int ks = 0; ks < 4; ++ks)
#pragma unroll
            for (int ct = 0; ct < 2; ++ct)
                bvA[ct][ks] = *(const bhalf8*)(bb + coladdr[ct] + ksoff[ks]);

        gen_dim(smem, 2 * p + 1, lrow0, half, areg[1]);   // A for odd dim (VALU)

#pragma unroll
        for (int ks = 0; ks < 4; ++ks)
#pragma unroll
            for (int rt = 0; rt < 2; ++rt)
#pragma unroll
                for (int ct = 0; ct < 2; ++ct)
                    acc[rt][ct] = __builtin_amdgcn_mfma_f32_32x32x16_bf16(
                        areg[0][rt][ks], bvA[ct][ks], acc[rt][ct], 0, 0, 0);

        bhalf8 bvB[2][4];
#pragma unroll
        for (int ks = 0; ks < 4; ++ks)
#pragma unroll
            for (int ct = 0; ct < 2; ++ct)
                bvB[ct][ks] = *(const bhalf8*)(bb + 32768 + coladdr[ct] + ksoff[ks]);

        if (p < PERIODS - 1)                   // A for next period's even dim
            gen_dim(smem, 2 * p + 2, lrow0, half, areg[0]);

#pragma unroll
        for (int ks = 0; ks < 4; ++ks)
#pragma unroll
            for (int rt = 0; rt < 2; ++rt)
#pragma unroll
                for (int ct = 0; ct < 2; ++ct)
                    acc[rt][ct] = __builtin_amdgcn_mfma_f32_32x32x16_bf16(
                        areg[1][rt][ks], bvB[ct][ks], acc[rt][ct], 0, 0, 0);

        __syncthreads();
    }

    // Epilogue: 32x32 C/D layout col=lane&31, row=(reg&3)+8*(reg>>2)+4*(lane>>5)
    // [measured m74/m101]. KSPLIT partials via device-scope atomics.
#pragma unroll
    for (int rt = 0; rt < 2; ++rt) {
#pragma unroll
        for (int ct = 0; ct < 2; ++ct) {
            const int col   = colbase + wc * 64 + ct * 32 + l31;
            const int rbase = rowbase + wr * 64 + rt * 32 + 4 * half;
#pragma unroll
            for (int reg = 0; reg < 16; ++reg) {
                const int row = rbase + (reg & 3) + 8 * (reg >> 2);
                atomicAdd(out + (size_t)row * OUTDIM + col, acc[rt][ct][reg]);
            }
        }
    }
}

// ---------------------------------------------------------------------------
// Fallback (only if ws too small for the 32MB bf16 B): slow but correct fp32.
// ---------------------------------------------------------------------------
__global__ __launch_bounds__(256) void fkan_naive(const float* __restrict__ x,
                                                  const float* __restrict__ coeffs,
                                                  const float* __restrict__ bias,
                                                  float* __restrict__ out) {
    const int b = blockIdx.x >> 1;
    const int o = ((blockIdx.x & 1) << 8) + threadIdx.x;
    float acc = bias[o];
    const float* xrow = x + (size_t)b * INDIM;
    for (int i = 0; i < INDIM; ++i) {
        const float rv = xrow[i] * INV2PI;
        const float cd = __builtin_amdgcn_cosf(rv);
        const float sd = __builtin_amdgcn_sinf(rv);
        float c = cd, s = sd;
        const float* cp = coeffs + (size_t)i * (KKDIM * OUTDIM) + o;
#pragma unroll 4
        for (int g = 0; g < NH; ++g) {
            acc += c * cp[g * 2 * OUTDIM] + s * cp[(g * 2 + 1) * OUTDIM];
            const float nc = c * cd - s * sd;
            const float ns = s * cd + c * sd;
            c = nc; s = ns;
        }
    }
    out[(size_t)b * OUTDIM + o] = acc;
}

extern "C" void kernel_launch(void* const* d_in, const int* in_sizes, int n_in,
                              void* d_out, int out_size, void* d_ws, size_t ws_size,
                              hipStream_t stream) {
    (void)in_sizes; (void)n_in; (void)out_size;
    const float* x      = (const float*)d_in[0];
    const float* coeffs = (const float*)d_in[1];
    const float* bias   = (const float*)d_in[2];
    float* out          = (float*)d_out;

    const size_t bt_bytes = (size_t)2 * INDIM * CHUNK_ELEMS * sizeof(unsigned short); // 32 MiB
    if (ws_size >= bt_bytes) {
        unsigned short* Bt = (unsigned short*)d_ws;
        fkan_prepass<<<2 * INDIM, 256, 0, stream>>>(coeffs, bias, out, Bt);  // 1024 blocks
        fkan_main<<<(BATCH / BM) * 2 * KSPLIT, THREADS, 0, stream>>>(x, Bt, out);  // 256 blocks
    } else {
        fkan_naive<<<BATCH * 2, 256, 0, stream>>>(x, coeffs, bias, out);
    }
}